// Round 3
// baseline (1601.337 us; speedup 1.0000x reference)
//
#include <hip/hip_runtime.h>
#include <stdint.h>

typedef unsigned int uint;

// B=2, N=5120, F=10240, H=W=256. Bit-exact fp32 replication of the reference
// (contract off, IEEE div). Pipeline:
//   transform -> per-face records -> bucket-sort faces by zmin (4096 buckets)
//   -> per-64px-strip wave scans faces in ascending-zmin order with early
//      termination (lb >= bestz+TOL for all lanes) -> fused bilinear sample.
// Winner = lexicographic (z, orig_f) min, identical to ref chunked argmin.
// Record = 4 float4: q0={xmin,xmax,ymin,ymax} q1={v0x,v0y,e1x,e1y}
//                    q2={e2x,e2y,inv,z0}      q3={z1,z2,bits(orig_f),lb}

#define K_BUCKETS 4096
#define ZLO 0.0f
#define ZHI 20.0f
#define TOL 1e-3f
#define CHUNK 32

__device__ __forceinline__ float clip11(float t) {
  return fminf(1.0f, fmaxf(-1.0f, t));
}

__global__ void k_zero(uint* __restrict__ p, int n) {
  int t = blockIdx.x * 256 + threadIdx.x;
  if (t < n) p[t] = 0u;
}

__global__ void k_transform(const float* __restrict__ hv,
                            const float* __restrict__ cam,
                            const float* __restrict__ camn,
                            float* __restrict__ pos,   // B*N*4
                            float* __restrict__ uv,    // B*N*2
                            int N, int B) {
#pragma clang fp contract(off)
  int t = blockIdx.x * 256 + threadIdx.x;
  if (t >= B * N) return;
  int b = t / N;
  float X0 = hv[t * 3 + 0];
  float X1 = hv[t * 3 + 1];
  float X2 = hv[t * 3 + 2];
  {
    float c0 = camn[b * 3 + 0], c1 = camn[b * 3 + 1], c2 = camn[b * 3 + 2];
    float t0 = c0 * (X0 + c1);
    float t1 = c0 * (X1 + c2);
    float t2 = c0 * X2;
    pos[t * 4 + 0] = clip11(t0);
    pos[t * 4 + 1] = clip11(-t1);
    pos[t * 4 + 2] = -t2 + 10.0f;
    pos[t * 4 + 3] = 0.0f;
  }
  {
    float c0 = cam[b * 3 + 0], c1 = cam[b * 3 + 1], c2 = cam[b * 3 + 2];
    float t0 = c0 * (X0 + c1);
    float t1 = c0 * (X1 + c2);
    uv[t * 2 + 0] = clip11(t0);
    uv[t * 2 + 1] = clip11(-t1);
  }
}

__global__ void k_faces(const int* __restrict__ faces,
                        const float* __restrict__ pos,
                        const float* __restrict__ uv,
                        float4* __restrict__ fh4,   // B*F*4 (orig order)
                        float4* __restrict__ fa4,   // B*F*2 (orig order)
                        uint* __restrict__ bkt,     // B*F
                        uint* __restrict__ cnt,     // B*K
                        int F, int N, int B) {
#pragma clang fp contract(off)
  int t = blockIdx.x * 256 + threadIdx.x;
  if (t >= B * F) return;
  int b = t / F;
  int f = t - b * F;
  int i0 = faces[f * 3 + 0];
  int i1 = faces[f * 3 + 1];
  int i2 = faces[f * 3 + 2];
  const float* p0 = pos + (size_t)(b * N + i0) * 4;
  const float* p1 = pos + (size_t)(b * N + i1) * 4;
  const float* p2 = pos + (size_t)(b * N + i2) * 4;
  float x0 = p0[0], y0 = p0[1], z0 = p0[2];
  float x1 = p1[0], y1 = p1[1], z1 = p1[2];
  float x2 = p2[0], y2 = p2[1], z2 = p2[2];
  float e1x = x1 - x0;
  float e1y = y1 - y0;
  float e2x = x2 - x0;
  float e2y = y2 - y0;
  float d = (e1x * e2y) - (e2x * e1y);
  float inv;
  if (fabsf(d) > 1e-8f) {
    inv = 1.0f / d;                     // IEEE division
  } else {
    inv = __int_as_float(0x7fc00000);   // NaN -> inside test fails
  }
  float4* fq = fh4 + (size_t)t * 4;
  fq[0] = make_float4(fminf(x0, fminf(x1, x2)), fmaxf(x0, fmaxf(x1, x2)),
                      fminf(y0, fminf(y1, y2)), fmaxf(y0, fmaxf(y1, y2)));
  fq[1] = make_float4(x0, y0, e1x, e1y);
  fq[2] = make_float4(e2x, e2y, inv, z0);
  fq[3] = make_float4(z1, z2, 0.0f, 0.0f);

  float zmn = fminf(z0, fminf(z1, z2));
  int kb = (int)((zmn - ZLO) * ((float)K_BUCKETS / (ZHI - ZLO)));
  kb = min(max(kb, 0), K_BUCKETS - 1);
  bkt[t] = (uint)kb;
  atomicAdd(&cnt[b * K_BUCKETS + kb], 1u);

  float u0 = uv[(size_t)(b * N + i0) * 2 + 0];
  float v0 = uv[(size_t)(b * N + i0) * 2 + 1];
  float u1 = uv[(size_t)(b * N + i1) * 2 + 0];
  float v1 = uv[(size_t)(b * N + i1) * 2 + 1];
  float u2 = uv[(size_t)(b * N + i2) * 2 + 0];
  float v2 = uv[(size_t)(b * N + i2) * 2 + 1];
  float4* aq = fa4 + (size_t)t * 2;
  aq[0] = make_float4(u0, v0, u1, v1);
  aq[1] = make_float4(u2, v2, 0.0f, 0.0f);
}

// one block per batch; exclusive prefix over K_BUCKETS counts
__global__ void __launch_bounds__(1024) k_prefix(const uint* __restrict__ cnt,
                                                 uint* __restrict__ off) {
  __shared__ uint s[1024];
  int b = blockIdx.x;
  const uint* c = cnt + (size_t)b * K_BUCKETS;
  uint* o = off + (size_t)b * K_BUCKETS;
  int tid = threadIdx.x;
  uint v0 = c[tid * 4 + 0], v1 = c[tid * 4 + 1], v2 = c[tid * 4 + 2], v3 = c[tid * 4 + 3];
  uint sum = v0 + v1 + v2 + v3;
  s[tid] = sum;
  __syncthreads();
  for (int d = 1; d < 1024; d <<= 1) {
    uint t = (tid >= d) ? s[tid - d] : 0u;
    __syncthreads();
    s[tid] += t;
    __syncthreads();
  }
  uint run = s[tid] - sum;   // exclusive
  o[tid * 4 + 0] = run; run += v0;
  o[tid * 4 + 1] = run; run += v1;
  o[tid * 4 + 2] = run; run += v2;
  o[tid * 4 + 3] = run;
}

__global__ void k_scatter(const float4* __restrict__ fh4,
                          const uint* __restrict__ bkt,
                          uint* __restrict__ off,       // consumed as cursor
                          float4* __restrict__ srec,    // B*F*4 sorted
                          int F, int B) {
  int t = blockIdx.x * 256 + threadIdx.x;
  if (t >= B * F) return;
  int b = t / F;
  int f = t - b * F;
  uint kb = bkt[t];
  uint pos = atomicAdd(&off[b * K_BUCKETS + kb], 1u);
  const float4* s = fh4 + (size_t)t * 4;
  float4 q0 = s[0], q1 = s[1], q2 = s[2], q3 = s[3];
  q3.z = __uint_as_float((uint)f);
  q3.w = (kb == 0u) ? -1e30f : (ZLO + (float)kb * ((ZHI - ZLO) / (float)K_BUCKETS));
  float4* d = srec + ((size_t)b * F + pos) * 4;
  d[0] = q0; d[1] = q1; d[2] = q2; d[3] = q3;
}

__device__ __forceinline__ float fetchpix(const float* __restrict__ img, int base,
                                          float ixf, float iyf) {
  bool valid = (ixf >= 0.0f) && (ixf < 256.0f) && (iyf >= 0.0f) && (iyf < 256.0f);
  int ix = (int)fminf(255.0f, fmaxf(0.0f, ixf));
  int iy = (int)fminf(255.0f, fmaxf(0.0f, iyf));
  float v = img[base + iy * 256 + ix];
  return valid ? v : 0.0f;
}

// one wave per 64-pixel strip: grid = B*256*4 blocks of 64 threads
__global__ void __launch_bounds__(64) k_raster(const float4* __restrict__ srec,
                                               const float4* __restrict__ fa4,
                                               const float* __restrict__ img,
                                               float* __restrict__ out,
                                               int F) {
#pragma clang fp contract(off)
  int blk = blockIdx.x;           // b*1024 + row*4 + q
  int q = blk & 3;
  int row = (blk >> 2) & 255;
  int b = blk >> 10;
  int lane = threadIdx.x;
  int col = q * 64 + lane;

  float px = (col + 0.5f) / 256.0f * 2.0f - 1.0f;
  float py = (row + 0.5f) / 256.0f * 2.0f - 1.0f;          // wave-uniform
  float pxlo = (q * 64 + 0.5f) / 256.0f * 2.0f - 1.0f;
  float pxhi = (q * 64 + 63 + 0.5f) / 256.0f * 2.0f - 1.0f;

  const float4* __restrict__ base4 = srec + (size_t)b * F * 4;
  __shared__ float4 lds[CHUNK * 4];

  float bestz = 1000000.0f;
  uint bestfo = 0xFFFFFFFFu;
  float bw0 = 0.0f, bw1 = 0.0f, bw2 = 0.0f;

  int total4 = F * 4;
  // prefetch chunk 0
  float4 r0, r1;
  {
    int e0 = lane * 2;
    if (e0 < total4)     r0 = base4[e0];
    if (e0 + 1 < total4) r1 = base4[e0 + 1];
  }

  for (int cb = 0; cb < F; cb += CHUNK) {
    int nf = min(CHUNK, F - cb);
    __syncthreads();
    {
      int e0 = cb * 4 + lane * 2;
      if (e0 < total4)     lds[lane * 2]     = r0;
      if (e0 + 1 < total4) lds[lane * 2 + 1] = r1;
    }
    __syncthreads();
    // issue next-chunk prefetch early
    int nb = cb + CHUNK;
    if (nb < F) {
      int e0 = nb * 4 + lane * 2;
      if (e0 < total4)     r0 = base4[e0];
      if (e0 + 1 < total4) r1 = base4[e0 + 1];
    }
    // early termination: lb of first face of chunk lower-bounds all remaining z
    float lb = lds[3].w;
    if (__all(lb >= bestz + TOL)) break;

    for (int k = 0; k < nf; ++k) {
      float4 q0 = lds[k * 4 + 0];
      // wave-uniform conservative bbox cull
      if (!(q0.z <= py && q0.w >= py && q0.x <= pxhi && q0.y >= pxlo))
        continue;
      float4 q1 = lds[k * 4 + 1];
      float4 q2 = lds[k * 4 + 2];
      float dpx = px - q1.x;
      float dpy = py - q1.y;
      float w1 = (dpx * q2.y - q2.x * dpy) * q2.z;
      float w2 = (q1.z * dpy - dpx * q1.w) * q2.z;
      float w0 = (1.0f - w1) - w2;
      if (w0 >= 0.0f && w1 >= 0.0f && w2 >= 0.0f) {
        float4 q3 = lds[k * 4 + 3];
        float z = (w0 * q2.w + w1 * q3.x) + w2 * q3.y;
        uint fo = __float_as_uint(q3.z);
        // lexicographic (z, orig_f): deterministic, matches ref tie-break
        if (z < bestz || (z == bestz && fo < bestfo)) {
          bestz = z;
          bestfo = fo;
          bw0 = w0; bw1 = w1; bw2 = w2;
        }
      }
    }
  }

  float gx = 0.0f, gy = 0.0f;
  if (bestfo != 0xFFFFFFFFu) {
    const float4* aq = fa4 + ((size_t)b * F + bestfo) * 2;
    float4 a0 = aq[0];
    float4 a1 = aq[1];
    gx = (bw0 * a0.x + bw1 * a0.z) + bw2 * a1.x;
    gy = (bw0 * a0.y + bw1 * a0.w) + bw2 * a1.y;
  }

  // grid_sample (align_corners=False, zero pad), exact ref op order
  float x = (gx + 1.0f) * 0.5f * 256.0f - 0.5f;
  float y = (gy + 1.0f) * 0.5f * 256.0f - 0.5f;
  float x0f = floorf(x), y0f = floorf(y);
  float wx1 = x - x0f, wx0 = 1.0f - wx1;
  float wy1 = y - y0f, wy0 = 1.0f - wy1;

  int pix = row * 256 + col;
  for (int c = 0; c < 3; ++c) {
    int base = (b * 3 + c) * 65536;
    float f00 = fetchpix(img, base, x0f, y0f);
    float f10 = fetchpix(img, base, x0f + 1.0f, y0f);
    float f01 = fetchpix(img, base, x0f, y0f + 1.0f);
    float f11 = fetchpix(img, base, x0f + 1.0f, y0f + 1.0f);
    float A  = wy0 * ((wx0 * f00) + (wx1 * f10));
    float Bv = wy1 * ((wx0 * f01) + (wx1 * f11));
    out[base + pix] = A + Bv;
  }
}

extern "C" void kernel_launch(void* const* d_in, const int* in_sizes, int n_in,
                              void* d_out, int out_size, void* d_ws, size_t ws_size,
                              hipStream_t stream) {
  const float* cam  = (const float*)d_in[0];
  const float* hv   = (const float*)d_in[1];
  const float* img  = (const float*)d_in[2];
  const float* camn = (const float*)d_in[3];
  const int* faces  = (const int*)d_in[4];

  const int B = in_sizes[0] / 3;            // 2
  const int N = in_sizes[1] / (3 * B);      // 5120
  const int F = in_sizes[4] / 3;            // 10240

  char* wsb = (char*)d_ws;
  size_t ofs = 0;
  float* pos = (float*)(wsb + ofs); ofs += (size_t)B * N * 4 * 4;
  float* uv  = (float*)(wsb + ofs); ofs += (size_t)B * N * 2 * 4;
  ofs = (ofs + 255) & ~(size_t)255;
  float4* fh4  = (float4*)(wsb + ofs); ofs += (size_t)B * F * 4 * sizeof(float4);
  float4* fa4  = (float4*)(wsb + ofs); ofs += (size_t)B * F * 2 * sizeof(float4);
  float4* srec = (float4*)(wsb + ofs); ofs += (size_t)B * F * 4 * sizeof(float4);
  uint* bkt = (uint*)(wsb + ofs); ofs += (size_t)B * F * 4;
  uint* cnt = (uint*)(wsb + ofs); ofs += (size_t)B * K_BUCKETS * 4;
  uint* off = (uint*)(wsb + ofs); ofs += (size_t)B * K_BUCKETS * 4;

  int nz = B * K_BUCKETS;
  k_zero<<<(nz + 255) / 256, 256, 0, stream>>>(cnt, nz);
  int nv = B * N;
  k_transform<<<(nv + 255) / 256, 256, 0, stream>>>(hv, cam, camn, pos, uv, N, B);
  int nf = B * F;
  k_faces<<<(nf + 255) / 256, 256, 0, stream>>>(faces, pos, uv, fh4, fa4, bkt, cnt, F, N, B);
  k_prefix<<<B, 1024, 0, stream>>>(cnt, off);
  k_scatter<<<(nf + 255) / 256, 256, 0, stream>>>(fh4, bkt, off, srec, F, B);
  k_raster<<<B * 256 * 4, 64, 0, stream>>>(srec, fa4, img, (float*)d_out, F);
}